// Round 5
// baseline (178.339 us; speedup 1.0000x reference)
//
#include <hip/hip_runtime.h>
#include <math.h>

// Native clang vector for nontemporal builtins (HIP_vector_type is rejected).
typedef float fvec4 __attribute__((ext_vector_type(4)));

// my_ceil(y) = sum_{k=1..150} sigmoid(100(y-k)) + sigmoid(100(y+k)) - 150
// Closed form (verified passing, absmax 0.25 = reference scan's own noise):
//   r = rint(y), d = y - r, s = sigmoid(100 d)
//   r >=  1 : (r-1) + s
//   r <= -1 : r + s
//   r ==  0 : 0            (offset 0 excluded from the sum)
//   clamp to [-150, 150]
__device__ __forceinline__ float my_ceil1(float y) {
    float r = rintf(y);
    float d = y - r;
    float e = __expf(-100.0f * d);                 // v_mul + v_exp_f32
    float s = __builtin_amdgcn_rcpf(1.0f + e);     // 1-instr reciprocal (~1 ulp)
    float f = (r >= 1.0f) ? (r - 1.0f + s)
            : (r <= -1.0f) ? (r + s)
            : 0.0f;
    return fminf(fmaxf(f, -150.0f), 150.0f);
}

__device__ __forceinline__ fvec4 my_ceil4(fvec4 v, fvec4 kc) {
    fvec4 o;
    o.x = my_ceil1(v.x * kc.x);
    o.y = my_ceil1(v.y * kc.y);
    o.z = my_ceil1(v.z * kc.z);
    o.w = my_ceil1(v.w * kc.w);
    return o;
}

// One thread = 4 independent float4s (j, j+q, j+2q, j+3q): 4 loads issued
// back-to-back before any compute -> 4x memory-level parallelism. q % 3 == 0,
// so all four share one channel-group (single %3). launch_bounds(256,8) pins
// VGPR <= 64 -> 8 waves/SIMD (full occupancy). Nontemporal stores keep the
// output stream from evicting the L3-resident input.
__global__ __launch_bounds__(256, 8) void quan_ceil_kernel(
        const fvec4* __restrict__ x4,
        const float* __restrict__ kern,   // 12 floats (C=12), broadcast
        fvec4* __restrict__ o4,
        int q) {                           // n4/4, divisible by 3
    int j = blockIdx.x * blockDim.x + threadIdx.x;
    if (j >= q) return;

    const fvec4* k4 = reinterpret_cast<const fvec4*>(kern);
    int g = j % 3;
    // ternary select, NOT a runtime-indexed array (avoids scratch, rule #20)
    fvec4 kc = (g == 0) ? k4[0] : (g == 1) ? k4[1] : k4[2];

    // all four loads independent — compiler issues them before the exp chains
    fvec4 a = x4[j];
    fvec4 b = x4[j + q];
    fvec4 c = x4[j + 2 * q];
    fvec4 d = x4[j + 3 * q];

    fvec4 oa = my_ceil4(a, kc);
    fvec4 ob = my_ceil4(b, kc);
    fvec4 oc = my_ceil4(c, kc);
    fvec4 od = my_ceil4(d, kc);

    __builtin_nontemporal_store(oa, &o4[j]);
    __builtin_nontemporal_store(ob, &o4[j + q]);
    __builtin_nontemporal_store(oc, &o4[j + 2 * q]);
    __builtin_nontemporal_store(od, &o4[j + 3 * q]);
}

extern "C" void kernel_launch(void* const* d_in, const int* in_sizes, int n_in,
                              void* d_out, int out_size, void* d_ws, size_t ws_size,
                              hipStream_t stream) {
    const float* x = (const float*)d_in[0];
    const float* kern = (const float*)d_in[1];
    float* out = (float*)d_out;

    int n = in_sizes[0];   // 128*128*128*12 = 25,165,824
    int n4 = n / 4;        // 6,291,456 float4s
    int q = n4 / 4;        // 1,572,864 (divisible by 3: all 4 streams share %3)

    const int block = 256;
    int grid = (q + block - 1) / block;   // 6144 blocks — full coverage

    quan_ceil_kernel<<<grid, block, 0, stream>>>(
        reinterpret_cast<const fvec4*>(x), kern,
        reinterpret_cast<fvec4*>(out), q);
}

// Round 6
// 170.825 us; speedup vs baseline: 1.0440x; 1.0440x over previous
//
#include <hip/hip_runtime.h>
#include <math.h>

// Native clang vector (HIP_vector_type rejected by nontemporal builtins / asm "v").
typedef float fvec4 __attribute__((ext_vector_type(4)));

// my_ceil(y) = sum_{k=1..150} sigmoid(100(y-k)) + sigmoid(100(y+k)) - 150
// Closed form (verified passing, absmax 0.25 = reference scan's own noise):
//   r = rint(y), d = y - r, s = sigmoid(100 d)
//   r >=  1 : (r-1) + s ;  r <= -1 : r + s ;  r == 0 : 0 ; clamp [-150,150]
__device__ __forceinline__ float my_ceil1(float y) {
    float r = rintf(y);
    float d = y - r;
    float e = __expf(-100.0f * d);                 // v_mul + v_exp_f32
    float s = __builtin_amdgcn_rcpf(1.0f + e);     // 1-instr reciprocal (~1 ulp)
    float f = (r >= 1.0f) ? (r - 1.0f + s)
            : (r <= -1.0f) ? (r + s)
            : 0.0f;
    return fminf(fmaxf(f, -150.0f), 150.0f);
}

__device__ __forceinline__ fvec4 my_ceil4(fvec4 v, fvec4 kc) {
    fvec4 o;
    o.x = my_ceil1(v.x * kc.x);
    o.y = my_ceil1(v.y * kc.y);
    o.z = my_ceil1(v.z * kc.z);
    o.w = my_ceil1(v.w * kc.w);
    return o;
}

// Round-5 post-mortem: VGPR_Count=16 proved the compiler SERIALIZED the
// "independent" loads (1 outstanding load/wave -> 2.5 TB/s, latency-bound).
// Fix: 8 streams/thread + an asm liveness barrier that forces all 8 loaded
// vectors co-live, so 8 global_load_dwordx4 issue before any compute.
// q8 = n4/8 is divisible by 3, so all 8 streams share one channel-group.
__global__ __launch_bounds__(256, 4) void quan_ceil_kernel(
        const fvec4* __restrict__ x4,
        const float* __restrict__ kern,   // 12 floats (C=12), broadcast
        fvec4* __restrict__ o4,
        int q) {                           // n4/8, divisible by 3
    int j = blockIdx.x * blockDim.x + threadIdx.x;
    if (j >= q) return;

    const fvec4* k4 = reinterpret_cast<const fvec4*>(kern);
    int g = j % 3;
    // ternary select, NOT a runtime-indexed array (avoids scratch, rule #20)
    fvec4 kc = (g == 0) ? k4[0] : (g == 1) ? k4[1] : k4[2];

    fvec4 a0 = __builtin_nontemporal_load(&x4[j]);
    fvec4 a1 = __builtin_nontemporal_load(&x4[j + q]);
    fvec4 a2 = __builtin_nontemporal_load(&x4[j + 2 * q]);
    fvec4 a3 = __builtin_nontemporal_load(&x4[j + 3 * q]);
    fvec4 a4 = __builtin_nontemporal_load(&x4[j + 4 * q]);
    fvec4 a5 = __builtin_nontemporal_load(&x4[j + 5 * q]);
    fvec4 a6 = __builtin_nontemporal_load(&x4[j + 6 * q]);
    fvec4 a7 = __builtin_nontemporal_load(&x4[j + 7 * q]);
    // Liveness barrier: all 8 vectors must be materialized here -> compiler
    // must issue all 8 loads back-to-back BEFORE any compute (32 VGPRs live).
    asm volatile("" : "+v"(a0), "+v"(a1), "+v"(a2), "+v"(a3),
                      "+v"(a4), "+v"(a5), "+v"(a6), "+v"(a7));

    __builtin_nontemporal_store(my_ceil4(a0, kc), &o4[j]);
    __builtin_nontemporal_store(my_ceil4(a1, kc), &o4[j + q]);
    __builtin_nontemporal_store(my_ceil4(a2, kc), &o4[j + 2 * q]);
    __builtin_nontemporal_store(my_ceil4(a3, kc), &o4[j + 3 * q]);
    __builtin_nontemporal_store(my_ceil4(a4, kc), &o4[j + 4 * q]);
    __builtin_nontemporal_store(my_ceil4(a5, kc), &o4[j + 5 * q]);
    __builtin_nontemporal_store(my_ceil4(a6, kc), &o4[j + 6 * q]);
    __builtin_nontemporal_store(my_ceil4(a7, kc), &o4[j + 7 * q]);
}

extern "C" void kernel_launch(void* const* d_in, const int* in_sizes, int n_in,
                              void* d_out, int out_size, void* d_ws, size_t ws_size,
                              hipStream_t stream) {
    const float* x = (const float*)d_in[0];
    const float* kern = (const float*)d_in[1];
    float* out = (float*)d_out;

    int n = in_sizes[0];   // 128*128*128*12 = 25,165,824
    int n4 = n / 4;        // 6,291,456 float4s
    int q = n4 / 8;        // 786,432 (divisible by 3 AND by 256)

    const int block = 256;
    int grid = (q + block - 1) / block;   // 3072 blocks, exact coverage

    quan_ceil_kernel<<<grid, block, 0, stream>>>(
        reinterpret_cast<const fvec4*>(x), kern,
        reinterpret_cast<fvec4*>(out), q);
}